// Round 2
// baseline (905.450 us; speedup 1.0000x reference)
//
#include <hip/hip_runtime.h>

typedef __attribute__((ext_vector_type(8))) _Float16 half8;
typedef __attribute__((ext_vector_type(16))) float f32x16;

static __device__ const int d_LENS[14] = {4,3,2,1,2,3,2,3,2,1,1,3,2,3};
static __device__ const int d_RIDX[14][4] = {
  {0,1,16,17},{2,18,19,19},{3,4,4,4},{20,20,20,20},{7,8,8,8},{21,25,26,26},
  {5,22,22,22},{6,23,24,24},{9,27,27,27},{11,11,11,11},{29,29,29,29},
  {10,15,28,28},{12,30,30,30},{13,14,31,31}};

__device__ __forceinline__ float sigf(float v){
  return __builtin_amdgcn_rcpf(1.0f + __expf(-v));
}
__device__ __forceinline__ float tanhf2(float v){
  return 1.0f - 2.0f*__builtin_amdgcn_rcpf(1.0f + __expf(2.0f*v));
}

__device__ __forceinline__ void gload16(const void* g, void* l){
  __builtin_amdgcn_global_load_lds((const __attribute__((address_space(1))) void*)g,
                                   (__attribute__((address_space(3))) void*)l, 16, 0, 0);
}

// Stage one 64KB weight chunk (256 cols x 128 k, f16) into wb with XOR-16 swizzle.
// Physical LDS byte L = logical ^ ((n&15)<<4); source supplies the inverse.
__device__ __forceinline__ void stage_w(const _Float16* __restrict__ src, char* wb,
                                        int wv, int lane){
  #pragma unroll
  for (int i=0;i<8;i++){
    int L = wv*8192 + i*1024 + lane*16;
    int n = L >> 8;
    int wlog = (L & 255) ^ ((n & 15) << 4);
    gload16((const char*)src + n*256 + wlog, wb + L);
  }
}

// ---------------------------------------------------------------------------
// prep: f32 -> f16 weights, row-permuted n' = c*256 + u*128 + g*32 + v
// (n = g*128 + c*64 + u*32 + v, hcol = c*64 + u*32 + v), fused biases in n'.
// ---------------------------------------------------------------------------
__global__ void prep_k(const float* __restrict__ w_ih, const float* __restrict__ w_hh,
                       const float* __restrict__ b_ih, const float* __restrict__ b_hh,
                       _Float16* __restrict__ wih, _Float16* __restrict__ whh,
                       float* __restrict__ bias)
{
  int tid = blockIdx.x*256 + threadIdx.x;
  if (tid < 2*1835008){
    const float* src = (tid < 1835008) ? w_ih : w_hh;
    _Float16* dst    = (tid < 1835008) ? wih  : whh;
    int t  = (tid < 1835008) ? tid : (tid - 1835008);
    int k  = t & 127;
    int np = (t >> 7) & 511;
    int rd = t >> 16;
    int c = (np >> 8) & 1, uu = (np >> 7) & 1, g = (np >> 5) & 3, vv = np & 31;
    int n = g*128 + c*64 + uu*32 + vv;
    dst[t] = (_Float16)src[((size_t)rd*512 + n)*128 + k];
  } else {
    int t = tid - 2*1835008;
    if (t < 14336){
      int rd = t >> 9, np = t & 511;
      int c = (np >> 8) & 1, uu = (np >> 7) & 1, g = (np >> 5) & 3, vv = np & 31;
      int n = g*128 + c*64 + uu*32 + vv;
      bias[t] = b_ih[rd*512 + n] + b_hh[rd*512 + n];
    }
  }
}

// ---------------------------------------------------------------------------
// Main kernel: block = (region r, 128 batch rows). 512 thr / 8 waves.
// Wave wv: row-group wr=wv>>1 (32 rows), col-group u=wv&1 (32 h-cols/chunk).
// LDS: wb 64KB (one weight chunk, swizzled), hb 32KB (recurrent h, swizzled).
// Chunks (c=0,1 over 256 gate-cols) processed sequentially -> acc[4] only.
// ---------------------------------------------------------------------------
__global__ __launch_bounds__(512, 2) void lstm_k(
    const float* __restrict__ x, const _Float16* __restrict__ wih,
    const _Float16* __restrict__ whh, const float* __restrict__ bias,
    _Float16* __restrict__ hout, float* __restrict__ fout, int f16mode,
    float* __restrict__ part)
{
  extern __shared__ char smem[];
  char* wb = smem;                       // 64 KB
  char* hb = smem + 65536;               // 32 KB
  float* red = (float*)(smem + 65536);   // alias, used after last hb use

  const int tid  = threadIdx.x;
  const int lane = tid & 63;
  const int wv = tid >> 6;
  const int wr = wv >> 1;
  const int u  = wv & 1;
  const int v  = lane & 31;
  const int q  = lane >> 5;

  // XCD-pinned mapping: xcd = blockIdx.x % 8 owns a contiguous 112-block slice
  // of the region-major (r, btile) order -> same-region weights stay in one L2.
  int w = blockIdx.x;
  int j = (w & 7)*112 + (w >> 3);
  const int r  = j >> 6;
  const int bt = j & 63;
  const int b0 = bt << 7;
  const int len = d_LENS[r];

  float bf[2][4];
  #pragma unroll
  for (int c=0;c<2;c++)
    #pragma unroll
    for (int g=0;g<4;g++)
      bf[c][g] = bias[(size_t)r*1024 + c*256 + u*128 + g*32 + v];

  float cst[2][16];
  #pragma unroll
  for (int c=0;c<2;c++)
    #pragma unroll
    for (int e=0;e<16;e++) cst[c][e] = 0.0f;

  half8 xf[8];
  float hn[2][16];
  float lsum = 0.0f, lsq = 0.0f;

  for (int t=0; t<len; ++t){
    const int chan = d_RIDX[r][t];
    // x A-fragments for this step (reused for both chunks; also for bwd at last t)
    const float* xb = x + (((size_t)(b0 + wr*32 + v))*32 + chan)*128 + q*8;
    #pragma unroll
    for (int ks=0;ks<8;ks++){
      float4 a0 = *(const float4*)(xb + ks*16);
      float4 a1 = *(const float4*)(xb + ks*16 + 4);
      half8 a;
      a[0]=(_Float16)a0.x; a[1]=(_Float16)a0.y; a[2]=(_Float16)a0.z; a[3]=(_Float16)a0.w;
      a[4]=(_Float16)a1.x; a[5]=(_Float16)a1.y; a[6]=(_Float16)a1.z; a[7]=(_Float16)a1.w;
      xf[ks] = a;
    }
    const bool last = (t == len-1);

    #pragma unroll
    for (int c=0;c<2;c++){
      f32x16 acc[4];
      #pragma unroll
      for (int g=0;g<4;g++)
        #pragma unroll
        for (int e=0;e<16;e++) acc[g][e] = bf[c][g];

      __syncthreads();                                    // wb free
      stage_w(wih + ((size_t)r*1024 + c*256)*128, wb, wv, lane);
      __syncthreads();
      #pragma unroll
      for (int ks=0;ks<8;ks++){
        #pragma unroll
        for (int g=0;g<4;g++){
          int nl = u*128 + g*32 + v;
          half8 bb = *(const half8*)(wb + ((nl*256 + ks*32 + q*16) ^ ((nl&15)<<4)));
          acc[g] = __builtin_amdgcn_mfma_f32_32x32x16_f16(xf[ks], bb, acc[g], 0, 0, 0);
        }
      }
      if (t > 0){
        __syncthreads();
        stage_w(whh + ((size_t)r*1024 + c*256)*128, wb, wv, lane);
        __syncthreads();
        const int hrow = wr*32 + v;
        #pragma unroll
        for (int ks=0;ks<8;ks++){
          half8 a = *(const half8*)(hb + ((hrow*256 + ks*32 + q*16) ^ ((hrow&15)<<4)));
          #pragma unroll
          for (int g=0;g<4;g++){
            int nl = u*128 + g*32 + v;
            half8 bb = *(const half8*)(wb + ((nl*256 + ks*32 + q*16) ^ ((nl&15)<<4)));
            acc[g] = __builtin_amdgcn_mfma_f32_32x32x16_f16(a, bb, acc[g], 0, 0, 0);
          }
        }
      }
      // pointwise for this chunk's 32 h-cols
      #pragma unroll
      for (int e=0;e<16;e++){
        float iv = acc[0][e], fv = acc[1][e];
        float gv = acc[2][e], ov = acc[3][e];
        float cn = sigf(iv)*tanhf2(gv) + sigf(fv)*cst[c][e];
        cst[c][e] = cn;
        float hv = sigf(ov)*tanhf2(cn);
        if (last){
          _Float16 hh = (_Float16)hv;
          float hr = (float)hh;
          int row = b0 + wr*32 + (e&3) + ((e>>2)<<3) + (q<<2);
          int col = c*64 + u*32 + v;
          size_t o = ((size_t)row*14 + r)*256 + col;
          if (f16mode) hout[o] = hh; else fout[o] = hr;
          lsum += hr; lsq += hr*hr;
        } else {
          hn[c][e] = hv;
        }
      }
    }
    if (!last){
      __syncthreads();                 // all h-GEMM reads of old h done
      #pragma unroll
      for (int e=0;e<16;e++){
        int rl = wr*32 + (e&3) + ((e>>2)<<3) + (q<<2);
        *(_Float16*)(hb + ((rl*256 + (u*32+v)*2)      ^ ((rl&15)<<4))) = (_Float16)hn[0][e];
        *(_Float16*)(hb + ((rl*256 + (64+u*32+v)*2)   ^ ((rl&15)<<4))) = (_Float16)hn[1][e];
      }
    }
  }

  // ---- backward cell: h0=c0=0 -> gates = x_last*W_ih[:,1] + b. xf reused. ----
  #pragma unroll
  for (int c=0;c<2;c++){
    float bb2[4];
    #pragma unroll
    for (int g=0;g<4;g++)
      bb2[g] = bias[(size_t)r*1024 + 512 + c*256 + u*128 + g*32 + v];
    f32x16 acc[4];
    #pragma unroll
    for (int g=0;g<4;g++)
      #pragma unroll
      for (int e=0;e<16;e++) acc[g][e] = bb2[g];

    __syncthreads();
    stage_w(wih + (((size_t)r*2 + 1)*512 + c*256)*128, wb, wv, lane);
    __syncthreads();
    #pragma unroll
    for (int ks=0;ks<8;ks++){
      #pragma unroll
      for (int g=0;g<4;g++){
        int nl = u*128 + g*32 + v;
        half8 bb = *(const half8*)(wb + ((nl*256 + ks*32 + q*16) ^ ((nl&15)<<4)));
        acc[g] = __builtin_amdgcn_mfma_f32_32x32x16_f16(xf[ks], bb, acc[g], 0, 0, 0);
      }
    }
    #pragma unroll
    for (int e=0;e<16;e++){
      float iv = acc[0][e];
      float gv = acc[2][e], ov = acc[3][e];
      float cn = sigf(iv)*tanhf2(gv);
      float hv = sigf(ov)*tanhf2(cn);
      _Float16 hh = (_Float16)hv;
      float hr = (float)hh;
      int row = b0 + wr*32 + (e&3) + ((e>>2)<<3) + (q<<2);
      int col = 128 + c*64 + u*32 + v;
      size_t o = ((size_t)row*14 + r)*256 + col;
      if (f16mode) hout[o] = hh; else fout[o] = hr;
      lsum += hr; lsq += hr*hr;
    }
  }

  // ---- per-block partials ----
  #pragma unroll
  for (int off=32; off>0; off>>=1){
    lsum += __shfl_down(lsum, off);
    lsq  += __shfl_down(lsq, off);
  }
  __syncthreads();
  if (lane == 0){ red[wv] = lsum; red[8+wv] = lsq; }
  __syncthreads();
  if (tid == 0){
    float s = 0.0f, s2 = 0.0f;
    #pragma unroll
    for (int ww=0;ww<8;ww++){ s += red[ww]; s2 += red[8+ww]; }
    part[((size_t)r*64 + bt)*2]     = s;
    part[((size_t)r*64 + bt)*2 + 1] = s2;
  }
}

// ---------------------------------------------------------------------------
__global__ void stats_k(const float* __restrict__ part, const float* __restrict__ gamma,
                        const float* __restrict__ beta, float* __restrict__ stat)
{
  int r = blockIdx.x, l = threadIdx.x;
  float s  = part[((size_t)r*64 + l)*2];
  float s2 = part[((size_t)r*64 + l)*2 + 1];
  #pragma unroll
  for (int off=32; off>0; off>>=1){ s += __shfl_down(s, off); s2 += __shfl_down(s2, off); }
  if (l == 0){
    const float cnt = 2097152.0f;
    float m = s / cnt;
    float var = s2 / cnt - m*m;
    float rstd = rsqrtf(var + 1e-5f);
    float sc = gamma[r]*rstd;
    stat[r*2]   = sc;
    stat[r*2+1] = beta[r] - m*sc;
  }
}

__global__ void apply_f16(const _Float16* __restrict__ hst, const float* __restrict__ stat,
                          float* __restrict__ out)
{
  size_t i8 = (size_t)blockIdx.x*256 + threadIdx.x;    // 8 elems each
  uint4 vv = *(const uint4*)(hst + i8*8);
  int r = (int)((i8 >> 5) % 14);
  float sc = stat[r*2], sh = stat[r*2+1];
  const _Float16* hp = (const _Float16*)&vv;
  float4 o0, o1;
  o0.x = (float)hp[0]*sc + sh; o0.y = (float)hp[1]*sc + sh;
  o0.z = (float)hp[2]*sc + sh; o0.w = (float)hp[3]*sc + sh;
  o1.x = (float)hp[4]*sc + sh; o1.y = (float)hp[5]*sc + sh;
  o1.z = (float)hp[6]*sc + sh; o1.w = (float)hp[7]*sc + sh;
  ((float4*)out)[i8*2]     = o0;
  ((float4*)out)[i8*2 + 1] = o1;
}

__global__ void apply_f32(float* __restrict__ out, const float* __restrict__ stat)
{
  size_t idx = (size_t)blockIdx.x*256 + threadIdx.x;
  float4* p = (float4*)out + idx;
  float4 vv = *p;
  int r = (int)((idx >> 6) % 14);
  float sc = stat[r*2], sh = stat[r*2+1];
  vv.x = vv.x*sc + sh; vv.y = vv.y*sc + sh; vv.z = vv.z*sc + sh; vv.w = vv.w*sc + sh;
  *p = vv;
}

// ---------------------------------------------------------------------------
extern "C" void kernel_launch(void* const* d_in, const int* in_sizes, int n_in,
                              void* d_out, int out_size, void* d_ws, size_t ws_size,
                              hipStream_t stream)
{
  const float* x     = (const float*)d_in[0];
  const float* w_ih  = (const float*)d_in[1];
  const float* w_hh  = (const float*)d_in[2];
  const float* b_ih  = (const float*)d_in[3];
  const float* b_hh  = (const float*)d_in[4];
  const float* gamma = (const float*)d_in[5];
  const float* beta  = (const float*)d_in[6];
  float* out = (float*)d_out;

  const size_t HS = 29360128;               // h elements (B*14*256)
  const size_t wbytes = (size_t)1835008*2;  // one weight array, bytes
  const size_t tail = (14336 + 1792 + 28)*4;
  const size_t need_f16 = HS*2 + 2*wbytes + tail;

  char* wsp = (char*)d_ws;
  int f16mode = (ws_size >= need_f16) ? 1 : 0;

  _Float16* hstore; _Float16* wihp; _Float16* whhp;
  if (f16mode){
    hstore = (_Float16*)wsp;
    wihp = (_Float16*)(wsp + HS*2);
  } else {
    hstore = (_Float16*)wsp;  // unused
    wihp = (_Float16*)wsp;
  }
  whhp = wihp + 1835008;
  float* biasp = (float*)(whhp + 1835008);
  float* partp = biasp + 14336;
  float* statp = partp + 1792;

  prep_k<<<14392, 256, 0, stream>>>(w_ih, w_hh, b_ih, b_hh, wihp, whhp, biasp);
  lstm_k<<<896, 512, 98304, stream>>>(x, wihp, whhp, biasp,
                                      hstore, out, f16mode, partp);
  stats_k<<<14, 64, 0, stream>>>(partp, gamma, beta, statp);
  if (f16mode)
    apply_f16<<<14336, 256, 0, stream>>>(hstore, statp, out);
  else
    apply_f32<<<28672, 256, 0, stream>>>(out, statp);
}

// Round 3
// 562.097 us; speedup vs baseline: 1.6108x; 1.6108x over previous
//
#include <hip/hip_runtime.h>

typedef __attribute__((ext_vector_type(8))) _Float16 half8;
typedef __attribute__((ext_vector_type(16))) float f32x16;

static __device__ const int d_LENS[14] = {4,3,2,1,2,3,2,3,2,1,1,3,2,3};
static __device__ const int d_RIDX[14][4] = {
  {0,1,16,17},{2,18,19,19},{3,4,4,4},{20,20,20,20},{7,8,8,8},{21,25,26,26},
  {5,22,22,22},{6,23,24,24},{9,27,27,27},{11,11,11,11},{29,29,29,29},
  {10,15,28,28},{12,30,30,30},{13,14,31,31}};

// Work-balanced XCD map: each XCD gets exactly 256 block-len units.
// XCD d hosts all 64 btiles of regA[d], then nB[d] btiles of regB[d] from boff[d].
static __device__ const int d_nTot[8] = {64,96,96,128,128,128,128,128};
static __device__ const int d_regA[8] = {0,1,5,7,11,13,2,6};
static __device__ const int d_regB[8] = {0,12,12,3,9,10,4,8};
static __device__ const int d_boff[8] = {0,0,32,0,0,0,0,0};

__device__ __forceinline__ float sigf(float v){
  return __builtin_amdgcn_rcpf(1.0f + __expf(-v));
}
__device__ __forceinline__ float tanhf2(float v){
  return 1.0f - 2.0f*__builtin_amdgcn_rcpf(1.0f + __expf(2.0f*v));
}

__device__ __forceinline__ void gload16(const void* g, void* l){
  __builtin_amdgcn_global_load_lds((const __attribute__((address_space(1))) void*)g,
                                   (__attribute__((address_space(3))) void*)l, 16, 0, 0);
}

// Stage one 64KB weight chunk (256 cols x 128 k, f16) into wb with XOR-16 swizzle.
__device__ __forceinline__ void stage_w(const _Float16* __restrict__ src, char* wb,
                                        int wv, int lane){
  #pragma unroll
  for (int i=0;i<8;i++){
    int L = wv*8192 + i*1024 + lane*16;
    int n = L >> 8;
    int wlog = (L & 255) ^ ((n & 15) << 4);
    gload16((const char*)src + n*256 + wlog, wb + L);
  }
}

// ---------------------------------------------------------------------------
// prep: f32 -> f16 weights, row-permuted np = c*256 + u*128 + g*32 + v
// (orig n = g*128 + c*64 + u*32 + v; h-col = c*64 + u*32 + v), fused biases.
// ---------------------------------------------------------------------------
__global__ void prep_k(const float* __restrict__ w_ih, const float* __restrict__ w_hh,
                       const float* __restrict__ b_ih, const float* __restrict__ b_hh,
                       _Float16* __restrict__ wih, _Float16* __restrict__ whh,
                       float* __restrict__ bias)
{
  int tid = blockIdx.x*256 + threadIdx.x;
  if (tid < 2*1835008){
    const float* src = (tid < 1835008) ? w_ih : w_hh;
    _Float16* dst    = (tid < 1835008) ? wih  : whh;
    int t  = (tid < 1835008) ? tid : (tid - 1835008);
    int k  = t & 127;
    int np = (t >> 7) & 511;
    int rd = t >> 16;
    int c = (np >> 8) & 1, uu = (np >> 7) & 1, g = (np >> 5) & 3, vv = np & 31;
    int n = g*128 + c*64 + uu*32 + vv;
    dst[t] = (_Float16)src[((size_t)rd*512 + n)*128 + k];
  } else {
    int t = tid - 2*1835008;
    if (t < 14336){
      int rd = t >> 9, np = t & 511;
      int c = (np >> 8) & 1, uu = (np >> 7) & 1, g = (np >> 5) & 3, vv = np & 31;
      int n = g*128 + c*64 + uu*32 + vv;
      bias[t] = b_ih[rd*512 + n] + b_hh[rd*512 + n];
    }
  }
}

// ---------------------------------------------------------------------------
// Main kernel. Block = (region r, 128 batch rows), 512 thr / 8 waves.
// Wave wv: row-group wr=wv>>1 (32 rows), col-group u=wv&1.
// LDS: wb 64KB (weight chunk, swizzled), hb[2] 2x32KB (recurrent h, dbuf).
// Chunks c=0,1 sequential through pointwise -> only acc[4] live (AGPR).
// ---------------------------------------------------------------------------
__global__ __launch_bounds__(512, 2) void lstm_k(
    const float* __restrict__ x, const _Float16* __restrict__ wih,
    const _Float16* __restrict__ whh, const float* __restrict__ bias,
    _Float16* __restrict__ hout, float* __restrict__ fout, int f16mode,
    float* __restrict__ part)
{
  extern __shared__ char smem[];
  char* wb  = smem;                        // 64 KB
  char* hb0 = smem + 65536;                // 2 x 32 KB
  float* red = (float*)(smem + 131072);    // 64 B

  const int tid  = threadIdx.x;
  const int lane = tid & 63;
  const int wv = tid >> 6;
  const int wr = wv >> 1;
  const int u  = wv & 1;
  const int v  = lane & 31;
  const int q  = lane >> 5;

  const int xcd = blockIdx.x & 7;
  const int k   = blockIdx.x >> 3;
  if (k >= d_nTot[xcd]) return;            // uniform per block
  int r, bt;
  if (k < 64){ r = d_regA[xcd]; bt = k; }
  else       { r = d_regB[xcd]; bt = d_boff[xcd] + (k - 64); }
  const int b0 = bt << 7;
  const int len = d_LENS[r];

  float bf[2][4];
  #pragma unroll
  for (int c=0;c<2;c++)
    #pragma unroll
    for (int g=0;g<4;g++)
      bf[c][g] = bias[(size_t)r*1024 + c*256 + u*128 + g*32 + v];

  float cst[2][16];
  #pragma unroll
  for (int c=0;c<2;c++)
    #pragma unroll
    for (int e=0;e<16;e++) cst[c][e] = 0.0f;

  half8 xf[8];
  float lsum = 0.0f, lsq = 0.0f;

  for (int t=0; t<len; ++t){
    const int chan = d_RIDX[r][t];
    const float* xb = x + (((size_t)(b0 + wr*32 + v))*32 + chan)*128 + q*8;
    #pragma unroll
    for (int ks=0;ks<8;ks++){
      float4 a0 = *(const float4*)(xb + ks*16);
      float4 a1 = *(const float4*)(xb + ks*16 + 4);
      half8 a;
      a[0]=(_Float16)a0.x; a[1]=(_Float16)a0.y; a[2]=(_Float16)a0.z; a[3]=(_Float16)a0.w;
      a[4]=(_Float16)a1.x; a[5]=(_Float16)a1.y; a[6]=(_Float16)a1.z; a[7]=(_Float16)a1.w;
      xf[ks] = a;
    }
    const bool last = (t == len-1);
    char* hbr = hb0 + (((t+1)&1) << 15);   // read buf (written at t-1)
    char* hbw = hb0 + ((t&1) << 15);       // write buf for this step

    #pragma unroll
    for (int c=0;c<2;c++){
      f32x16 acc[4];
      #pragma unroll
      for (int g=0;g<4;g++)
        #pragma unroll
        for (int e=0;e<16;e++) acc[g][e] = bf[c][g];

      __syncthreads();                                    // wb free
      stage_w(wih + ((size_t)r*1024 + c*256)*128, wb, wv, lane);
      __syncthreads();
      #pragma unroll
      for (int ks=0;ks<8;ks++){
        #pragma unroll
        for (int g=0;g<4;g++){
          int nl = u*128 + g*32 + v;
          half8 bb = *(const half8*)(wb + ((nl*256 + ks*32 + q*16) ^ ((nl&15)<<4)));
          acc[g] = __builtin_amdgcn_mfma_f32_32x32x16_f16(xf[ks], bb, acc[g], 0, 0, 0);
        }
      }
      if (t > 0){
        __syncthreads();
        stage_w(whh + ((size_t)r*1024 + c*256)*128, wb, wv, lane);
        __syncthreads();
        const int hrow = wr*32 + v;
        #pragma unroll
        for (int ks=0;ks<8;ks++){
          half8 a = *(const half8*)(hbr + ((hrow*256 + ks*32 + q*16) ^ ((hrow&15)<<4)));
          #pragma unroll
          for (int g=0;g<4;g++){
            int nl = u*128 + g*32 + v;
            half8 bb = *(const half8*)(wb + ((nl*256 + ks*32 + q*16) ^ ((nl&15)<<4)));
            acc[g] = __builtin_amdgcn_mfma_f32_32x32x16_f16(a, bb, acc[g], 0, 0, 0);
          }
        }
      }
      // pointwise for this chunk's 32 h-cols; write h to LDS dbuf or global
      #pragma unroll
      for (int e=0;e<16;e++){
        float iv = acc[0][e], fv = acc[1][e];
        float gv = acc[2][e], ov = acc[3][e];
        float cn = sigf(iv)*tanhf2(gv) + sigf(fv)*cst[c][e];
        cst[c][e] = cn;
        float hv = sigf(ov)*tanhf2(cn);
        if (last){
          _Float16 hh = (_Float16)hv;
          float hr = (float)hh;
          int row = b0 + wr*32 + (e&3) + ((e>>2)<<3) + (q<<2);
          int col = c*64 + u*32 + v;
          size_t o = ((size_t)row*14 + r)*256 + col;
          if (f16mode) hout[o] = hh; else fout[o] = hr;
          lsum += hr; lsq += hr*hr;
        } else {
          int rl = wr*32 + (e&3) + ((e>>2)<<3) + (q<<2);
          *(_Float16*)(hbw + ((rl*256 + (c*64 + u*32 + v)*2) ^ ((rl&15)<<4)))
              = (_Float16)hv;
        }
      }
    }
  }

  // ---- backward cell: h0=c0=0 -> gates = x_last*W_ih[:,1] + b. xf reused. ----
  #pragma unroll
  for (int c=0;c<2;c++){
    float bb2[4];
    #pragma unroll
    for (int g=0;g<4;g++)
      bb2[g] = bias[(size_t)r*1024 + 512 + c*256 + u*128 + g*32 + v];
    f32x16 acc[4];
    #pragma unroll
    for (int g=0;g<4;g++)
      #pragma unroll
      for (int e=0;e<16;e++) acc[g][e] = bb2[g];

    __syncthreads();
    stage_w(wih + (((size_t)r*2 + 1)*512 + c*256)*128, wb, wv, lane);
    __syncthreads();
    #pragma unroll
    for (int ks=0;ks<8;ks++){
      #pragma unroll
      for (int g=0;g<4;g++){
        int nl = u*128 + g*32 + v;
        half8 bb = *(const half8*)(wb + ((nl*256 + ks*32 + q*16) ^ ((nl&15)<<4)));
        acc[g] = __builtin_amdgcn_mfma_f32_32x32x16_f16(xf[ks], bb, acc[g], 0, 0, 0);
      }
    }
    #pragma unroll
    for (int e=0;e<16;e++){
      float iv = acc[0][e];
      float gv = acc[2][e], ov = acc[3][e];
      float cn = sigf(iv)*tanhf2(gv);
      float hv = sigf(ov)*tanhf2(cn);
      _Float16 hh = (_Float16)hv;
      float hr = (float)hh;
      int row = b0 + wr*32 + (e&3) + ((e>>2)<<3) + (q<<2);
      int col = 128 + c*64 + u*32 + v;
      size_t o = ((size_t)row*14 + r)*256 + col;
      if (f16mode) hout[o] = hh; else fout[o] = hr;
      lsum += hr; lsq += hr*hr;
    }
  }

  // ---- per-block partials ----
  #pragma unroll
  for (int off=32; off>0; off>>=1){
    lsum += __shfl_down(lsum, off);
    lsq  += __shfl_down(lsq, off);
  }
  __syncthreads();
  if (lane == 0){ red[wv] = lsum; red[8+wv] = lsq; }
  __syncthreads();
  if (tid == 0){
    float s = 0.0f, s2 = 0.0f;
    #pragma unroll
    for (int ww=0;ww<8;ww++){ s += red[ww]; s2 += red[8+ww]; }
    part[((size_t)r*64 + bt)*2]     = s;
    part[((size_t)r*64 + bt)*2 + 1] = s2;
  }
}

// ---------------------------------------------------------------------------
__global__ void stats_k(const float* __restrict__ part, const float* __restrict__ gamma,
                        const float* __restrict__ beta, float* __restrict__ stat)
{
  int r = blockIdx.x, l = threadIdx.x;
  float s  = part[((size_t)r*64 + l)*2];
  float s2 = part[((size_t)r*64 + l)*2 + 1];
  #pragma unroll
  for (int off=32; off>0; off>>=1){ s += __shfl_down(s, off); s2 += __shfl_down(s2, off); }
  if (l == 0){
    const float cnt = 2097152.0f;
    float m = s / cnt;
    float var = s2 / cnt - m*m;
    float rstd = rsqrtf(var + 1e-5f);
    float sc = gamma[r]*rstd;
    stat[r*2]   = sc;
    stat[r*2+1] = beta[r] - m*sc;
  }
}

__global__ void apply_f16(const _Float16* __restrict__ hst, const float* __restrict__ stat,
                          float* __restrict__ out)
{
  size_t i8 = (size_t)blockIdx.x*256 + threadIdx.x;    // 8 elems each
  uint4 vv = *(const uint4*)(hst + i8*8);
  int r = (int)((i8 >> 5) % 14);
  float sc = stat[r*2], sh = stat[r*2+1];
  const _Float16* hp = (const _Float16*)&vv;
  float4 o0, o1;
  o0.x = (float)hp[0]*sc + sh; o0.y = (float)hp[1]*sc + sh;
  o0.z = (float)hp[2]*sc + sh; o0.w = (float)hp[3]*sc + sh;
  o1.x = (float)hp[4]*sc + sh; o1.y = (float)hp[5]*sc + sh;
  o1.z = (float)hp[6]*sc + sh; o1.w = (float)hp[7]*sc + sh;
  ((float4*)out)[i8*2]     = o0;
  ((float4*)out)[i8*2 + 1] = o1;
}

__global__ void apply_f32(float* __restrict__ out, const float* __restrict__ stat)
{
  size_t idx = (size_t)blockIdx.x*256 + threadIdx.x;
  float4* p = (float4*)out + idx;
  float4 vv = *p;
  int r = (int)((idx >> 6) % 14);
  float sc = stat[r*2], sh = stat[r*2+1];
  vv.x = vv.x*sc + sh; vv.y = vv.y*sc + sh; vv.z = vv.z*sc + sh; vv.w = vv.w*sc + sh;
  *p = vv;
}

// ---------------------------------------------------------------------------
extern "C" void kernel_launch(void* const* d_in, const int* in_sizes, int n_in,
                              void* d_out, int out_size, void* d_ws, size_t ws_size,
                              hipStream_t stream)
{
  const float* x     = (const float*)d_in[0];
  const float* w_ih  = (const float*)d_in[1];
  const float* w_hh  = (const float*)d_in[2];
  const float* b_ih  = (const float*)d_in[3];
  const float* b_hh  = (const float*)d_in[4];
  const float* gamma = (const float*)d_in[5];
  const float* beta  = (const float*)d_in[6];
  float* out = (float*)d_out;

  const size_t HS = 29360128;               // h elements (B*14*256)
  const size_t wbytes = (size_t)1835008*2;  // one weight array, bytes
  const size_t tail = (14336 + 1792 + 28)*4;
  const size_t need_f16 = HS*2 + 2*wbytes + tail;

  char* wsp = (char*)d_ws;
  int f16mode = (ws_size >= need_f16) ? 1 : 0;

  _Float16* hstore; _Float16* wihp; _Float16* whhp;
  if (f16mode){
    hstore = (_Float16*)wsp;
    wihp = (_Float16*)(wsp + HS*2);
  } else {
    hstore = (_Float16*)wsp;  // unused
    wihp = (_Float16*)wsp;
  }
  whhp = wihp + 1835008;
  float* biasp = (float*)(whhp + 1835008);
  float* partp = biasp + 14336;
  float* statp = partp + 1792;

  prep_k<<<14392, 256, 0, stream>>>(w_ih, w_hh, b_ih, b_hh, wihp, whhp, biasp);
  lstm_k<<<1024, 512, 131136, stream>>>(x, wihp, whhp, biasp,
                                        hstore, out, f16mode, partp);
  stats_k<<<14, 64, 0, stream>>>(partp, gamma, beta, statp);
  if (f16mode)
    apply_f16<<<14336, 256, 0, stream>>>(hstore, statp, out);
  else
    apply_f32<<<28672, 256, 0, stream>>>(out, statp);
}